// Round 1
// baseline (1056.788 us; speedup 1.0000x reference)
//
#include <hip/hip_runtime.h>

typedef _Float16 half8 __attribute__((ext_vector_type(8)));
typedef float floatx4 __attribute__((ext_vector_type(4)));

constexpr int Bn = 16, Cn = 256, Hn = 64, Wn = 96;
constexpr int HW = Hn * Wn;          // 6144
constexpr int Dn = 21, ND = Dn * Dn; // 441
constexpr int TY = 8, TX = 8;
constexpr int NTY = Hn / TY;         // 8
constexpr int NTX = Wn / TX;         // 12
constexpr int NI = (TY + 40) / 2;    // 24 class-window rows
constexpr int NJ = (TX + 40) / 2;    // 24 class-window cols
constexpr int NN = NI * NJ;          // 576
constexpr int NTILES = NN / 16;      // 36 n-tiles of 16
constexpr int GP = 580;              // padded LDS pitch (580%32=4 -> conflict-free deposits)

// One workgroup = (batch b, 8x8 spatial tile, parity class).
// Per class: G[m=16 p1 pixels][n=576 window pixels] = sum_c f1[c,p1]*f2[c,p2]
// via mfma_f32_16x16x32_f16; then gather G -> 441 displacement channels.
__global__ __launch_bounds__(256, 4)
void corr_mfma(const float* __restrict__ f1, const float* __restrict__ f2,
               float* __restrict__ out) {
  __shared__ float G[16 * GP];

  const int bid = blockIdx.x;
  const int cls = bid & 3;
  const int t2  = bid >> 2;
  const int tx  = t2 % NTX;
  const int t3  = t2 / NTX;
  const int ty  = t3 % NTY;
  const int b   = t3 / NTY;
  const int qa = cls >> 1, qb = cls & 1;
  const int y0 = ty * TY, x0 = tx * TX;

  const int lane = threadIdx.x & 63;
  const int wave = threadIdx.x >> 6;   // 0..3
  const int l15  = lane & 15;
  const int lk   = lane >> 4;          // k-group 0..3

  const float* f1b = f1 + b * (Cn * HW);
  const float* f2b = f2 + b * (Cn * HW);

  // ---- A fragments: p1 pixel m=l15 at (y0+qa+2*(m>>2), x0+qb+2*(m&3)),
  //      channels k = ks*32 + lk*8 + t. Held in registers for the whole wave.
  const int ay = y0 + qa + 2 * (l15 >> 2);
  const int ax = x0 + qb + 2 * (l15 & 3);
  const float* f1p = f1b + ay * Wn + ax;
  half8 afrag[8];
#pragma unroll
  for (int ks = 0; ks < 8; ++ks) {
#pragma unroll
    for (int t = 0; t < 8; ++t) {
      const int c = ks * 32 + lk * 8 + t;
      afrag[ks][t] = (_Float16)f1p[c * HW];
    }
  }

  // ---- main loop: 9 n-tiles per wave, B-fragments straight from global fp32
  const int nt0 = wave * (NTILES / 4);
  for (int nt = nt0; nt < nt0 + NTILES / 4; ++nt) {
    const unsigned n = nt * 16 + l15;
    const int i = n / (unsigned)NJ;
    const int j = n % (unsigned)NJ;
    const int y2 = y0 - 20 + qa + 2 * i;
    const int x2 = x0 - 20 + qb + 2 * j;
    const bool inb = (y2 >= 0) & (y2 < Hn) & (x2 >= 0) & (x2 < Wn);
    const float* f2p = f2b + (inb ? (y2 * Wn + x2) : 0);

    floatx4 acc = {0.f, 0.f, 0.f, 0.f};
#pragma unroll
    for (int ks = 0; ks < 8; ++ks) {
      half8 bfrag;
#pragma unroll
      for (int t = 0; t < 8; ++t) {
        const int c = ks * 32 + lk * 8 + t;
        const float v = f2p[c * HW];
        bfrag[t] = (_Float16)(inb ? v : 0.0f);
      }
      acc = __builtin_amdgcn_mfma_f32_16x16x32_f16(afrag[ks], bfrag, acc, 0, 0, 0);
    }
    // deposit: lane l reg r holds G[m = 4*lk + r][n]
#pragma unroll
    for (int r = 0; r < 4; ++r) {
      const int m = 4 * lk + r;
      G[m * GP + n] = acc[r];
    }
  }
  __syncthreads();

  // ---- epilogue: out[b, dy*21+dx, y0+qa+2a, x0+qb+2b] = G[a*4+b][(a+dy)*24+(b+dx)]/C
  float* outb = out + b * (ND * HW);
  const float invc = 1.0f / 256.0f;
  for (int o = threadIdx.x; o < ND * 16; o += 256) {
    const int d = o >> 4;
    const int m = o & 15;
    const unsigned du = (unsigned)d;
    const int dy = du / 21u;
    const int dx = du % 21u;
    const int alpha = m >> 2, beta = m & 3;
    const float val = G[m * GP + (alpha + dy) * NJ + (beta + dx)] * invc;
    const int yy = y0 + qa + 2 * alpha;
    const int xx = x0 + qb + 2 * beta;
    outb[d * HW + yy * Wn + xx] = val;
  }
}

extern "C" void kernel_launch(void* const* d_in, const int* in_sizes, int n_in,
                              void* d_out, int out_size, void* d_ws, size_t ws_size,
                              hipStream_t stream) {
  const float* f1 = (const float*)d_in[0];
  const float* f2 = (const float*)d_in[1];
  float* out = (float*)d_out;
  dim3 grid(Bn * NTY * NTX * 4);  // 6144 workgroups, class fastest-varying
  corr_mfma<<<grid, dim3(256), 0, stream>>>(f1, f2, out);
}

// Round 2
// 350.020 us; speedup vs baseline: 3.0192x; 3.0192x over previous
//
#include <hip/hip_runtime.h>

typedef _Float16 half8 __attribute__((ext_vector_type(8)));
typedef float floatx4 __attribute__((ext_vector_type(4)));

constexpr int Bn = 16, Cn = 256, Hn = 64, Wn = 96;
constexpr int HW = Hn * Wn;          // 6144
constexpr int Dn = 21, ND = Dn * Dn; // 441
// padded f2 spatial dims (pad=20 each side)
constexpr int PH = Hn + 40;          // 104
constexpr int PW = Wn + 40;          // 136
constexpr int PHW = PH * PW;         // 14144
// pass-2 tile
constexpr int TY = 8, TX = 16;
constexpr int NTY = Hn / TY;         // 8
constexpr int NTX = Wn / TX;         // 6
constexpr int NI = (TY + 40) / 2;    // 24 class-window rows
constexpr int NJ = (TX + 40) / 2;    // 28 class-window cols
constexpr int NN = NI * NJ;          // 672
constexpr int NT = NN / 16;          // 42 n-tiles
constexpr int Mrows = 32;            // p1 pixels per class (4x8 grid)
constexpr int GPITCH = 676;          // f16 pitch: 4-row delta = 8 banks -> conflict-free deposits

constexpr size_t F1T_BYTES = (size_t)Bn * HW * Cn * 2;   // 50,331,648
constexpr size_t F2T_BYTES = (size_t)Bn * PHW * Cn * 2;  // 115,867,648
constexpr size_t WS_NEEDED = F1T_BYTES + F2T_BYTES;

// ---------------- pass 1a: f1 [B,C,H,W] f32 -> [B,HW,C] f16 (LDS-free) ----
__global__ __launch_bounds__(256)
void tconv_f1(const float* __restrict__ in, _Float16* __restrict__ outp) {
  const int blk = blockIdx.x;
  const int b = blk / (HW / 64);
  const int px0 = (blk % (HW / 64)) * 64;
  const int t = threadIdx.x;
  const int pxl = t >> 2;            // 0..63
  const int g = t & 3;
  const int px = px0 + pxl;
  const float* src = in + (size_t)b * Cn * HW + px;
  _Float16* dst = outp + ((size_t)b * HW + px) * Cn;
#pragma unroll
  for (int it = 0; it < 8; ++it) {
    const int c0 = (g + it * 4) * 8;
    half8 v;
#pragma unroll
    for (int k = 0; k < 8; ++k)
      v[k] = (_Float16)src[(size_t)(c0 + k) * HW];
    *(half8*)(dst + c0) = v;         // 16B store, lanes g=0..3 contiguous 64B
  }
}

// ---------------- pass 1b: f2 -> zero-padded [B,PH*PW,C] f16 --------------
__global__ __launch_bounds__(256)
void tconv_f2pad(const float* __restrict__ in, _Float16* __restrict__ outp) {
  const int blk = blockIdx.x;
  const int b = blk / (PHW / 64);
  const int ppx0 = (blk % (PHW / 64)) * 64;
  const int t = threadIdx.x;
  const int pxl = t >> 2;
  const int g = t & 3;
  const int ppx = ppx0 + pxl;
  const int y = ppx / PW;
  const int x = ppx - y * PW;
  const int yy = y - 20, xx = x - 20;
  const bool valid = (yy >= 0) & (yy < Hn) & (xx >= 0) & (xx < Wn);
  const float* src = in + (size_t)b * Cn * HW + (valid ? (yy * Wn + xx) : 0);
  _Float16* dst = outp + ((size_t)b * PHW + ppx) * Cn;
#pragma unroll
  for (int it = 0; it < 8; ++it) {
    const int c0 = (g + it * 4) * 8;
    half8 v;
#pragma unroll
    for (int k = 0; k < 8; ++k) {
      const float f = src[(size_t)(c0 + k) * HW];
      v[k] = (_Float16)(valid ? f : 0.0f);
    }
    *(half8*)(dst + c0) = v;
  }
}

// ---------------- pass 2: correlation via MFMA ----------------------------
// One wg = one 8x16 tile, all 4 parity classes sequentially.
// Per class: G[m=32][n=672] = f1_tile(32px) . f2_window(24x28px) over C=256,
// via mfma_f32_16x16x32_f16; G (f16, pre-scaled 1/C) -> LDS -> gather epilogue.
__global__ __launch_bounds__(256, 3)
void corr2(const _Float16* __restrict__ f1t, const _Float16* __restrict__ f2t,
           float* __restrict__ out) {
  __shared__ _Float16 G[Mrows * GPITCH];  // 43,264 B -> 3 wg/CU

  // bijective XCD swizzle: 768 wgs = 8 XCDs x 96 contiguous tiles
  int bid = (int)blockIdx.x;
  bid = (bid & 7) * 96 + (bid >> 3);
  const int tx = bid % NTX;
  const int tmp = bid / NTX;
  const int ty = tmp % NTY;
  const int b = tmp / NTY;
  const int y0 = ty * TY, x0 = tx * TX;

  const int t = threadIdx.x;
  const int lane = t & 63;
  const int wave = t >> 6;
  const int l15 = lane & 15;
  const int lk = lane >> 4;

  const _Float16* f1b = f1t + (size_t)b * HW * Cn;
  const _Float16* f2b = f2t + (size_t)b * PHW * Cn;

  const int nt_begin = (wave < 2) ? wave * 11 : 22 + (wave - 2) * 10;
  const int nt_count = (wave < 2) ? 11 : 10;
  const float invc = 1.0f / 256.0f;

  for (int cls = 0; cls < 4; ++cls) {
    const int qa = cls >> 1, qb = cls & 1;

    // A fragments for both m-tiles, held in registers (64 VGPR)
    half8 afrag[2][8];
#pragma unroll
    for (int mt = 0; mt < 2; ++mt) {
      const int m = mt * 16 + l15;
      const int ay = y0 + qa + 2 * (m >> 3);
      const int ax = x0 + qb + 2 * (m & 7);
      const _Float16* ap = f1b + (size_t)(ay * Wn + ax) * Cn + lk * 8;
#pragma unroll
      for (int ks = 0; ks < 8; ++ks)
        afrag[mt][ks] = *(const half8*)(ap + ks * 32);
    }

    for (int nt = nt_begin; nt < nt_begin + nt_count; ++nt) {
      const int n = nt * 16 + l15;
      const int i = n / NJ;
      const int j = n - i * NJ;
      const int py = y0 + qa + 2 * i;     // padded coords: (y0-20+qa+2i)+20
      const int px = x0 + qb + 2 * j;
      const _Float16* bp = f2b + (size_t)(py * PW + px) * Cn + lk * 8;
      half8 bfrag[8];
#pragma unroll
      for (int ks = 0; ks < 8; ++ks)
        bfrag[ks] = *(const half8*)(bp + ks * 32);

      floatx4 acc0 = {0.f, 0.f, 0.f, 0.f};
      floatx4 acc1 = {0.f, 0.f, 0.f, 0.f};
#pragma unroll
      for (int ks = 0; ks < 8; ++ks) {
        acc0 = __builtin_amdgcn_mfma_f32_16x16x32_f16(afrag[0][ks], bfrag[ks], acc0, 0, 0, 0);
        acc1 = __builtin_amdgcn_mfma_f32_16x16x32_f16(afrag[1][ks], bfrag[ks], acc1, 0, 0, 0);
      }
#pragma unroll
      for (int r = 0; r < 4; ++r) {
        G[(4 * lk + r) * GPITCH + n]        = (_Float16)(acc0[r] * invc);
        G[(16 + 4 * lk + r) * GPITCH + n]   = (_Float16)(acc1[r] * invc);
      }
    }
    __syncthreads();

    // epilogue: out[b, dy*21+dx, y0+qa+2a, x0+qb+2b] = G[m][(a+dy)*NJ + (b+dx)]
    {
      const int m = t & 31;
      const int alpha = m >> 3, beta = m & 7;
      const int yy = y0 + qa + 2 * alpha;
      const int xx = x0 + qb + 2 * beta;
      float* ob = out + (size_t)b * ND * HW + yy * Wn + xx;
      const _Float16* Grow = G + m * GPITCH + alpha * NJ + beta;
      int d = t >> 5;  // 0..7 (<21 so dy starts 0)
      int dy = 0, dx = d;
      while (d < ND) {
        ob[(size_t)d * HW] = (float)Grow[dy * NJ + dx];
        d += 8;
        dx += 8;
        if (dx >= Dn) { dx -= Dn; dy += 1; }
      }
    }
    __syncthreads();
  }
}

// ---------------- fallback (round-1 kernel) if ws too small ---------------
constexpr int FTY = 8, FTX = 8;
constexpr int FNTY = Hn / FTY, FNTX = Wn / FTX;
constexpr int FNJ = 24, FNTILES = 36, FGP = 580;

__global__ __launch_bounds__(256, 4)
void corr_fallback(const float* __restrict__ f1, const float* __restrict__ f2,
                   float* __restrict__ out) {
  __shared__ float G[16 * FGP];
  const int bid = blockIdx.x;
  const int cls = bid & 3;
  const int t2 = bid >> 2;
  const int tx = t2 % FNTX;
  const int t3 = t2 / FNTX;
  const int ty = t3 % FNTY;
  const int b = t3 / FNTY;
  const int qa = cls >> 1, qb = cls & 1;
  const int y0 = ty * FTY, x0 = tx * FTX;
  const int lane = threadIdx.x & 63;
  const int wave = threadIdx.x >> 6;
  const int l15 = lane & 15;
  const int lk = lane >> 4;
  const float* f1b = f1 + b * (Cn * HW);
  const float* f2b = f2 + b * (Cn * HW);
  const int ay = y0 + qa + 2 * (l15 >> 2);
  const int ax = x0 + qb + 2 * (l15 & 3);
  const float* f1p = f1b + ay * Wn + ax;
  half8 afrag[8];
#pragma unroll
  for (int ks = 0; ks < 8; ++ks)
#pragma unroll
    for (int tt = 0; tt < 8; ++tt)
      afrag[ks][tt] = (_Float16)f1p[(ks * 32 + lk * 8 + tt) * HW];
  const int nt0 = wave * (FNTILES / 4);
  for (int nt = nt0; nt < nt0 + FNTILES / 4; ++nt) {
    const unsigned n = nt * 16 + l15;
    const int i = n / (unsigned)FNJ;
    const int j = n % (unsigned)FNJ;
    const int y2 = y0 - 20 + qa + 2 * i;
    const int x2 = x0 - 20 + qb + 2 * j;
    const bool inb = (y2 >= 0) & (y2 < Hn) & (x2 >= 0) & (x2 < Wn);
    const float* f2p = f2b + (inb ? (y2 * Wn + x2) : 0);
    floatx4 acc = {0.f, 0.f, 0.f, 0.f};
#pragma unroll
    for (int ks = 0; ks < 8; ++ks) {
      half8 bfrag;
#pragma unroll
      for (int tt = 0; tt < 8; ++tt) {
        const float v = f2p[(ks * 32 + lk * 8 + tt) * HW];
        bfrag[tt] = (_Float16)(inb ? v : 0.0f);
      }
      acc = __builtin_amdgcn_mfma_f32_16x16x32_f16(afrag[ks], bfrag, acc, 0, 0, 0);
    }
#pragma unroll
    for (int r = 0; r < 4; ++r)
      G[(4 * lk + r) * FGP + n] = acc[r];
  }
  __syncthreads();
  float* outb = out + b * (ND * HW);
  const float invc = 1.0f / 256.0f;
  for (int o = threadIdx.x; o < ND * 16; o += 256) {
    const int d = o >> 4;
    const int m = o & 15;
    const int dy = (unsigned)d / 21u;
    const int dx = (unsigned)d % 21u;
    const int alpha = m >> 2, beta = m & 3;
    const float val = G[m * FGP + (alpha + dy) * FNJ + (beta + dx)] * invc;
    outb[d * HW + (y0 + qa + 2 * alpha) * Wn + (x0 + qb + 2 * beta)] = val;
  }
}

extern "C" void kernel_launch(void* const* d_in, const int* in_sizes, int n_in,
                              void* d_out, int out_size, void* d_ws, size_t ws_size,
                              hipStream_t stream) {
  const float* f1 = (const float*)d_in[0];
  const float* f2 = (const float*)d_in[1];
  float* out = (float*)d_out;
  if (ws_size >= WS_NEEDED) {
    _Float16* f1t = (_Float16*)d_ws;
    _Float16* f2t = (_Float16*)((char*)d_ws + F1T_BYTES);
    tconv_f1<<<dim3(Bn * (HW / 64)), dim3(256), 0, stream>>>(f1, f1t);
    tconv_f2pad<<<dim3(Bn * (PHW / 64)), dim3(256), 0, stream>>>(f2, f2t);
    corr2<<<dim3(Bn * NTY * NTX), dim3(256), 0, stream>>>(f1t, f2t, out);
  } else {
    corr_fallback<<<dim3(Bn * FNTY * FNTX * 4), dim3(256), 0, stream>>>(f1, f2, out);
  }
}